// Round 1
// baseline (949.213 us; speedup 1.0000x reference)
//
#include <hip/hip_runtime.h>
#include <math.h>

#define GRID_R 128
#define DATA_DIM 28
#define MAX_STEPS 256
#define STEP_SIZE 0.001f
#define BG 1.0f

__global__ __launch_bounds__(256) void VolumeRenderer_kernel(
    const float* __restrict__ tree,
    const float* __restrict__ origins,
    const float* __restrict__ dirs_in,
    const float* __restrict__ viewdirs,
    const float* __restrict__ invradius,
    float* __restrict__ out, int nB)
{
    int i = blockIdx.x * blockDim.x + threadIdx.x;
    if (i >= nB) return;

    float ox = origins[3*i+0], oy = origins[3*i+1], oz = origins[3*i+2];
    float dx = dirs_in[3*i+0], dy = dirs_in[3*i+1], dz = dirs_in[3*i+2];
    float vx = viewdirs[3*i+0], vy = viewdirs[3*i+1], vz = viewdirs[3*i+2];
    float irx = invradius[0], iry = invradius[1], irz = invradius[2];

    // normalize dirs
    float dn = sqrtf(dx*dx + dy*dy + dz*dz);
    float rdn = 1.0f / dn;
    dx *= rdn; dy *= rdn; dz *= rdn;

    // SH basis (degree 2) from viewdirs
    const float C0 = 0.28209479177387814f;
    const float C1 = 0.4886025119029199f;
    float sh0 = C0;
    float sh1 = -C1 * vy;
    float sh2 =  C1 * vz;
    float sh3 = -C1 * vx;
    float sh4 =  1.0925484305920792f  * vx * vy;
    float sh5 = -1.0925484305920792f * vy * vz;
    float sh6 =  0.31539156525252005f * (2.0f*vz*vz - vx*vx - vy*vy);
    float sh7 = -1.0925484305920792f * vx * vz;
    float sh8 =  0.5462742152960396f  * (vx*vx - vy*vy);

    float idx = 1.0f / (dx + 1e-9f);
    float idy = 1.0f / (dy + 1e-9f);
    float idz = 1.0f / (dz + 1e-9f);

    // dda_unit(origins, invdirs)
    float t1x = -ox*idx, t1y = -oy*idy, t1z = -oz*idz;
    float t2x = t1x+idx, t2y = t1y+idy, t2z = t1z+idz;
    float t0   = fmaxf(fmaxf(fmaxf(fminf(t1x,t2x), fminf(t1y,t2y)), fminf(t1z,t2z)), 0.0f);
    float tmax = fminf(fminf(fminf(fmaxf(t1x,t2x), fmaxf(t1y,t2y)), fmaxf(t1z,t2z)), 1e9f);

    // delta_scale = |dirs / invradius|
    float qx = dx / irx, qy = dy / iry, qz = dz / irz;
    float delta_scale = sqrtf(qx*qx + qy*qy + qz*qz);

    float t = t0;
    float light = 1.0f;
    float o0 = 0.0f, o1 = 0.0f, o2 = 0.0f;

    if (t0 < tmax) {
        const float Rf = (float)GRID_R;
        const float cube_sz = 1.0f / (float)GRID_R;
        for (int s = 0; s < MAX_STEPS; ++s) {
            // pos * R
            float px = (ox + t*dx) * Rf;
            float py = (oy + t*dy) * Rf;
            float pz = (oz + t*dz) * Rf;
            float fx = fminf(fmaxf(floorf(px), 0.0f), Rf - 1.0f);
            float fy = fminf(fmaxf(floorf(py), 0.0f), Rf - 1.0f);
            float fz = fminf(fmaxf(floorf(pz), 0.0f), Rf - 1.0f);
            int flat = (int)fx * (GRID_R*GRID_R) + (int)fy * GRID_R + (int)fz;

            // gather voxel: 28 floats = 7 x float4, 16B-aligned (28*4 = 112 B)
            const float4* vox = (const float4*)(tree + (size_t)flat * DATA_DIM);
            float4 va = vox[0];
            float4 vb = vox[1];
            float4 vc = vox[2];
            float4 vd = vox[3];
            float4 ve = vox[4];
            float4 vf = vox[5];
            float4 vg = vox[6];

            // per-cell dda on pos_t = pos*R - idx
            float cx = px - fx, cy = py - fy, cz = pz - fz;
            float a1x = -cx*idx, a1y = -cy*idy, a1z = -cz*idz;
            float a2x = a1x+idx, a2y = a1y+idy, a2z = a1z+idz;
            float s0 = fmaxf(fmaxf(fmaxf(fminf(a1x,a2x), fminf(a1y,a2y)), fminf(a1z,a2z)), 0.0f);
            float s1 = fminf(fminf(fminf(fmaxf(a1x,a2x), fmaxf(a1y,a2y)), fmaxf(a1z,a2z)), 1e9f);
            float dt = (s1 - s0) * cube_sz + STEP_SIZE;

            float sigma = fmaxf(vg.w, 0.0f);
            float att = __expf(-dt * sigma * delta_scale);
            float weight = light * (1.0f - att);

            // SH dot products: ch0 = rgba[0..8], ch1 = rgba[9..17], ch2 = rgba[18..26]
            float r0 = sh0*va.x + sh1*va.y + sh2*va.z + sh3*va.w
                     + sh4*vb.x + sh5*vb.y + sh6*vb.z + sh7*vb.w + sh8*vc.x;
            float r1 = sh0*vc.y + sh1*vc.z + sh2*vc.w + sh3*vd.x
                     + sh4*vd.y + sh5*vd.z + sh6*vd.w + sh7*ve.x + sh8*ve.y;
            float r2 = sh0*ve.z + sh1*ve.w + sh2*vf.x + sh3*vf.y
                     + sh4*vf.z + sh5*vf.w + sh6*vg.x + sh7*vg.y + sh8*vg.z;

            // sigmoid
            float g0 = 1.0f / (1.0f + __expf(-r0));
            float g1 = 1.0f / (1.0f + __expf(-r1));
            float g2 = 1.0f / (1.0f + __expf(-r2));

            o0 += weight * g0;
            o1 += weight * g1;
            o2 += weight * g2;

            light *= att;
            t += dt;
            if (t >= tmax) break;
            if (light < 1e-7f) break;   // remaining contribution bounded by 1e-7
        }
    }

    out[3*i+0] = o0 + light * BG;
    out[3*i+1] = o1 + light * BG;
    out[3*i+2] = o2 + light * BG;
}

extern "C" void kernel_launch(void* const* d_in, const int* in_sizes, int n_in,
                              void* d_out, int out_size, void* d_ws, size_t ws_size,
                              hipStream_t stream) {
    const float* tree      = (const float*)d_in[0];
    const float* origins   = (const float*)d_in[1];
    const float* dirs      = (const float*)d_in[2];
    const float* viewdirs  = (const float*)d_in[3];
    const float* invradius = (const float*)d_in[4];
    float* out = (float*)d_out;

    int nB = in_sizes[1] / 3;
    const int block = 256;
    int grid = (nB + block - 1) / block;
    VolumeRenderer_kernel<<<grid, block, 0, stream>>>(
        tree, origins, dirs, viewdirs, invradius, out, nB);
}

// Round 2
// 841.952 us; speedup vs baseline: 1.1274x; 1.1274x over previous
//
#include <hip/hip_runtime.h>
#include <hip/hip_fp16.h>
#include <math.h>

#define GRID_R 128
#define DATA_DIM 28
#define PAD_DIM 32
#define MAX_STEPS 256
#define STEP_SIZE 0.001f
#define BG 1.0f

// ---------------------------------------------------------------------------
// Pre-pass: fp32 grid (28 floats/voxel) -> fp16 grid (32 halfs/voxel, 64 B
// aligned records). One thread per 4 elements.
// ---------------------------------------------------------------------------
__global__ __launch_bounds__(256) void convert_kernel(
    const float* __restrict__ tree, __half* __restrict__ dst, int nvox)
{
    int d = blockIdx.x * blockDim.x + threadIdx.x;
    int v = d >> 3;          // voxel
    int j = d & 7;           // 4-element chunk within voxel (0..6 real, 7 pad)
    if (v >= nvox || j == 7) return;
    const float4 s = *(const float4*)(tree + (size_t)v * DATA_DIM + j * 4);
    union { uint2 u; __half2 h[2]; } w;
    w.h[0] = __floats2half2_rn(s.x, s.y);
    w.h[1] = __floats2half2_rn(s.z, s.w);
    *(uint2*)(dst + (size_t)v * PAD_DIM + j * 4) = w.u;
}

// ---------------------------------------------------------------------------
// Main ray-march, fp16 grid in workspace
// ---------------------------------------------------------------------------
__global__ __launch_bounds__(256) void VolumeRenderer_kernel_h(
    const __half* __restrict__ vox_grid,
    const float* __restrict__ origins,
    const float* __restrict__ dirs_in,
    const float* __restrict__ viewdirs,
    const float* __restrict__ invradius,
    float* __restrict__ out, int nB)
{
    int i = blockIdx.x * blockDim.x + threadIdx.x;
    if (i >= nB) return;

    float ox = origins[3*i+0], oy = origins[3*i+1], oz = origins[3*i+2];
    float dx = dirs_in[3*i+0], dy = dirs_in[3*i+1], dz = dirs_in[3*i+2];
    float vx = viewdirs[3*i+0], vy = viewdirs[3*i+1], vz = viewdirs[3*i+2];
    float irx = invradius[0], iry = invradius[1], irz = invradius[2];

    float dn = sqrtf(dx*dx + dy*dy + dz*dz);
    float rdn = 1.0f / dn;
    dx *= rdn; dy *= rdn; dz *= rdn;

    const float C0 = 0.28209479177387814f;
    const float C1 = 0.4886025119029199f;
    float sh0 = C0;
    float sh1 = -C1 * vy;
    float sh2 =  C1 * vz;
    float sh3 = -C1 * vx;
    float sh4 =  1.0925484305920792f  * vx * vy;
    float sh5 = -1.0925484305920792f * vy * vz;
    float sh6 =  0.31539156525252005f * (2.0f*vz*vz - vx*vx - vy*vy);
    float sh7 = -1.0925484305920792f * vx * vz;
    float sh8 =  0.5462742152960396f  * (vx*vx - vy*vy);

    float idx = 1.0f / (dx + 1e-9f);
    float idy = 1.0f / (dy + 1e-9f);
    float idz = 1.0f / (dz + 1e-9f);

    float t1x = -ox*idx, t1y = -oy*idy, t1z = -oz*idz;
    float t2x = t1x+idx, t2y = t1y+idy, t2z = t1z+idz;
    float t0   = fmaxf(fmaxf(fmaxf(fminf(t1x,t2x), fminf(t1y,t2y)), fminf(t1z,t2z)), 0.0f);
    float tmax = fminf(fminf(fminf(fmaxf(t1x,t2x), fmaxf(t1y,t2y)), fmaxf(t1z,t2z)), 1e9f);

    float qx = dx / irx, qy = dy / iry, qz = dz / irz;
    float delta_scale = sqrtf(qx*qx + qy*qy + qz*qz);

    float t = t0;
    float light = 1.0f;
    float o0 = 0.0f, o1 = 0.0f, o2 = 0.0f;

    if (t0 < tmax) {
        const float Rf = (float)GRID_R;
        const float cube_sz = 1.0f / (float)GRID_R;
        for (int s = 0; s < MAX_STEPS; ++s) {
            float px = (ox + t*dx) * Rf;
            float py = (oy + t*dy) * Rf;
            float pz = (oz + t*dz) * Rf;
            float fx = fminf(fmaxf(floorf(px), 0.0f), Rf - 1.0f);
            float fy = fminf(fmaxf(floorf(py), 0.0f), Rf - 1.0f);
            float fz = fminf(fmaxf(floorf(pz), 0.0f), Rf - 1.0f);
            int flat = (int)fx * (GRID_R*GRID_R) + (int)fy * GRID_R + (int)fz;

            // 64 B record: 4 x 16 B loads
            const uint4* vp = (const uint4*)(vox_grid + (size_t)flat * PAD_DIM);
            union U { uint4 u[4]; __half2 h[16]; } rec;
            rec.u[0] = vp[0];
            rec.u[1] = vp[1];
            rec.u[2] = vp[2];
            rec.u[3] = vp[3];

            // per-cell DDA overlaps the loads
            float cx = px - fx, cy = py - fy, cz = pz - fz;
            float a1x = -cx*idx, a1y = -cy*idy, a1z = -cz*idz;
            float a2x = a1x+idx, a2y = a1y+idy, a2z = a1z+idz;
            float s0 = fmaxf(fmaxf(fmaxf(fminf(a1x,a2x), fminf(a1y,a2y)), fminf(a1z,a2z)), 0.0f);
            float s1 = fminf(fminf(fminf(fmaxf(a1x,a2x), fmaxf(a1y,a2y)), fmaxf(a1z,a2z)), 1e9f);
            float dt = (s1 - s0) * cube_sz + STEP_SIZE;

            float2 p0  = __half22float2(rec.h[0]);
            float2 p1  = __half22float2(rec.h[1]);
            float2 p2  = __half22float2(rec.h[2]);
            float2 p3  = __half22float2(rec.h[3]);
            float2 p4  = __half22float2(rec.h[4]);
            float2 p5  = __half22float2(rec.h[5]);
            float2 p6  = __half22float2(rec.h[6]);
            float2 p7  = __half22float2(rec.h[7]);
            float2 p8  = __half22float2(rec.h[8]);
            float2 p9  = __half22float2(rec.h[9]);
            float2 p10 = __half22float2(rec.h[10]);
            float2 p11 = __half22float2(rec.h[11]);
            float2 p12 = __half22float2(rec.h[12]);
            float2 p13 = __half22float2(rec.h[13]);

            float sigma = fmaxf(p13.y, 0.0f);
            float att = __expf(-dt * sigma * delta_scale);
            float weight = light * (1.0f - att);

            float r0 = sh0*p0.x + sh1*p0.y + sh2*p1.x + sh3*p1.y
                     + sh4*p2.x + sh5*p2.y + sh6*p3.x + sh7*p3.y + sh8*p4.x;
            float r1 = sh0*p4.y + sh1*p5.x + sh2*p5.y + sh3*p6.x
                     + sh4*p6.y + sh5*p7.x + sh6*p7.y + sh7*p8.x + sh8*p8.y;
            float r2 = sh0*p9.x + sh1*p9.y + sh2*p10.x + sh3*p10.y
                     + sh4*p11.x + sh5*p11.y + sh6*p12.x + sh7*p12.y + sh8*p13.x;

            float g0 = 1.0f / (1.0f + __expf(-r0));
            float g1 = 1.0f / (1.0f + __expf(-r1));
            float g2 = 1.0f / (1.0f + __expf(-r2));

            o0 += weight * g0;
            o1 += weight * g1;
            o2 += weight * g2;

            light *= att;
            t += dt;
            if (t >= tmax) break;
            if (light < 1e-7f) break;
        }
    }

    out[3*i+0] = o0 + light * BG;
    out[3*i+1] = o1 + light * BG;
    out[3*i+2] = o2 + light * BG;
}

// ---------------------------------------------------------------------------
// Fallback: original fp32 path (used only if ws too small)
// ---------------------------------------------------------------------------
__global__ __launch_bounds__(256) void VolumeRenderer_kernel_f32(
    const float* __restrict__ tree,
    const float* __restrict__ origins,
    const float* __restrict__ dirs_in,
    const float* __restrict__ viewdirs,
    const float* __restrict__ invradius,
    float* __restrict__ out, int nB)
{
    int i = blockIdx.x * blockDim.x + threadIdx.x;
    if (i >= nB) return;

    float ox = origins[3*i+0], oy = origins[3*i+1], oz = origins[3*i+2];
    float dx = dirs_in[3*i+0], dy = dirs_in[3*i+1], dz = dirs_in[3*i+2];
    float vx = viewdirs[3*i+0], vy = viewdirs[3*i+1], vz = viewdirs[3*i+2];
    float irx = invradius[0], iry = invradius[1], irz = invradius[2];

    float dn = sqrtf(dx*dx + dy*dy + dz*dz);
    float rdn = 1.0f / dn;
    dx *= rdn; dy *= rdn; dz *= rdn;

    const float C0 = 0.28209479177387814f;
    const float C1 = 0.4886025119029199f;
    float sh0 = C0;
    float sh1 = -C1 * vy;
    float sh2 =  C1 * vz;
    float sh3 = -C1 * vx;
    float sh4 =  1.0925484305920792f  * vx * vy;
    float sh5 = -1.0925484305920792f * vy * vz;
    float sh6 =  0.31539156525252005f * (2.0f*vz*vz - vx*vx - vy*vy);
    float sh7 = -1.0925484305920792f * vx * vz;
    float sh8 =  0.5462742152960396f  * (vx*vx - vy*vy);

    float idx = 1.0f / (dx + 1e-9f);
    float idy = 1.0f / (dy + 1e-9f);
    float idz = 1.0f / (dz + 1e-9f);

    float t1x = -ox*idx, t1y = -oy*idy, t1z = -oz*idz;
    float t2x = t1x+idx, t2y = t1y+idy, t2z = t1z+idz;
    float t0   = fmaxf(fmaxf(fmaxf(fminf(t1x,t2x), fminf(t1y,t2y)), fminf(t1z,t2z)), 0.0f);
    float tmax = fminf(fminf(fminf(fmaxf(t1x,t2x), fmaxf(t1y,t2y)), fmaxf(t1z,t2z)), 1e9f);

    float qx = dx / irx, qy = dy / iry, qz = dz / irz;
    float delta_scale = sqrtf(qx*qx + qy*qy + qz*qz);

    float t = t0;
    float light = 1.0f;
    float o0 = 0.0f, o1 = 0.0f, o2 = 0.0f;

    if (t0 < tmax) {
        const float Rf = (float)GRID_R;
        const float cube_sz = 1.0f / (float)GRID_R;
        for (int s = 0; s < MAX_STEPS; ++s) {
            float px = (ox + t*dx) * Rf;
            float py = (oy + t*dy) * Rf;
            float pz = (oz + t*dz) * Rf;
            float fx = fminf(fmaxf(floorf(px), 0.0f), Rf - 1.0f);
            float fy = fminf(fmaxf(floorf(py), 0.0f), Rf - 1.0f);
            float fz = fminf(fmaxf(floorf(pz), 0.0f), Rf - 1.0f);
            int flat = (int)fx * (GRID_R*GRID_R) + (int)fy * GRID_R + (int)fz;

            const float4* vox = (const float4*)(tree + (size_t)flat * DATA_DIM);
            float4 va = vox[0]; float4 vb = vox[1]; float4 vc = vox[2];
            float4 vd = vox[3]; float4 ve = vox[4]; float4 vf = vox[5];
            float4 vg = vox[6];

            float cx = px - fx, cy = py - fy, cz = pz - fz;
            float a1x = -cx*idx, a1y = -cy*idy, a1z = -cz*idz;
            float a2x = a1x+idx, a2y = a1y+idy, a2z = a1z+idz;
            float s0 = fmaxf(fmaxf(fmaxf(fminf(a1x,a2x), fminf(a1y,a2y)), fminf(a1z,a2z)), 0.0f);
            float s1 = fminf(fminf(fminf(fmaxf(a1x,a2x), fmaxf(a1y,a2y)), fmaxf(a1z,a2z)), 1e9f);
            float dt = (s1 - s0) * cube_sz + STEP_SIZE;

            float sigma = fmaxf(vg.w, 0.0f);
            float att = __expf(-dt * sigma * delta_scale);
            float weight = light * (1.0f - att);

            float r0 = sh0*va.x + sh1*va.y + sh2*va.z + sh3*va.w
                     + sh4*vb.x + sh5*vb.y + sh6*vb.z + sh7*vb.w + sh8*vc.x;
            float r1 = sh0*vc.y + sh1*vc.z + sh2*vc.w + sh3*vd.x
                     + sh4*vd.y + sh5*vd.z + sh6*vd.w + sh7*ve.x + sh8*ve.y;
            float r2 = sh0*ve.z + sh1*ve.w + sh2*vf.x + sh3*vf.y
                     + sh4*vf.z + sh5*vf.w + sh6*vg.x + sh7*vg.y + sh8*vg.z;

            float g0 = 1.0f / (1.0f + __expf(-r0));
            float g1 = 1.0f / (1.0f + __expf(-r1));
            float g2 = 1.0f / (1.0f + __expf(-r2));

            o0 += weight * g0;
            o1 += weight * g1;
            o2 += weight * g2;

            light *= att;
            t += dt;
            if (t >= tmax) break;
            if (light < 1e-7f) break;
        }
    }

    out[3*i+0] = o0 + light * BG;
    out[3*i+1] = o1 + light * BG;
    out[3*i+2] = o2 + light * BG;
}

extern "C" void kernel_launch(void* const* d_in, const int* in_sizes, int n_in,
                              void* d_out, int out_size, void* d_ws, size_t ws_size,
                              hipStream_t stream) {
    const float* tree      = (const float*)d_in[0];
    const float* origins   = (const float*)d_in[1];
    const float* dirs      = (const float*)d_in[2];
    const float* viewdirs  = (const float*)d_in[3];
    const float* invradius = (const float*)d_in[4];
    float* out = (float*)d_out;

    int nB   = in_sizes[1] / 3;
    int nvox = in_sizes[0] / DATA_DIM;

    size_t need = (size_t)nvox * PAD_DIM * sizeof(__half);
    const int block = 256;

    if (ws_size >= need) {
        __half* hgrid = (__half*)d_ws;
        int nconv = nvox * 8;  // one thread per 4 dst elements
        convert_kernel<<<(nconv + block - 1) / block, block, 0, stream>>>(
            tree, hgrid, nvox);
        VolumeRenderer_kernel_h<<<(nB + block - 1) / block, block, 0, stream>>>(
            hgrid, origins, dirs, viewdirs, invradius, out, nB);
    } else {
        VolumeRenderer_kernel_f32<<<(nB + block - 1) / block, block, 0, stream>>>(
            tree, origins, dirs, viewdirs, invradius, out, nB);
    }
}

// Round 3
// 822.414 us; speedup vs baseline: 1.1542x; 1.0238x over previous
//
#include <hip/hip_runtime.h>
#include <hip/hip_fp16.h>
#include <math.h>

#define GRID_R 128
#define DATA_DIM 28
#define PAD_DIM 32
#define MAX_STEPS 256
#define STEP_SIZE 0.001f
#define BG 1.0f

// ---------------------------------------------------------------------------
// Pre-pass: fp32 grid (28 floats/voxel) -> fp16 grid (32 halfs/voxel, 64 B
// aligned records). One thread per 4 elements.
// ---------------------------------------------------------------------------
__global__ __launch_bounds__(256) void convert_kernel(
    const float* __restrict__ tree, __half* __restrict__ dst, int nvox)
{
    int d = blockIdx.x * blockDim.x + threadIdx.x;
    int v = d >> 3;          // voxel
    int j = d & 7;           // 4-element chunk within voxel (0..6 real, 7 pad)
    if (v >= nvox || j == 7) return;
    const float4 s = *(const float4*)(tree + (size_t)v * DATA_DIM + j * 4);
    union { uint2 u; __half2 h[2]; } w;
    w.h[0] = __floats2half2_rn(s.x, s.y);
    w.h[1] = __floats2half2_rn(s.z, s.w);
    *(uint2*)(dst + (size_t)v * PAD_DIM + j * 4) = w.u;
}

// ---------------------------------------------------------------------------
// Main ray-march, fp16 grid, depth-4 software-pipelined gather.
// Trajectory (voxel index + dt per step) is data-independent, so we march
// geometry 4 steps ahead of consumption; 16 dwordx4 loads in flight/lane.
// Grid supplies only 4 waves/SIMD (262144 rays), so ILP is the only latency
// hiding available; VGPR<=128 keeps all 4 waves resident.
// ---------------------------------------------------------------------------
__global__ __launch_bounds__(256, 4) void VolumeRenderer_kernel_h(
    const __half* __restrict__ vox_grid,
    const float* __restrict__ origins,
    const float* __restrict__ dirs_in,
    const float* __restrict__ viewdirs,
    const float* __restrict__ invradius,
    float* __restrict__ out, int nB)
{
    int i = blockIdx.x * blockDim.x + threadIdx.x;
    if (i >= nB) return;

    float ox = origins[3*i+0], oy = origins[3*i+1], oz = origins[3*i+2];
    float dx = dirs_in[3*i+0], dy = dirs_in[3*i+1], dz = dirs_in[3*i+2];
    float vx = viewdirs[3*i+0], vy = viewdirs[3*i+1], vz = viewdirs[3*i+2];
    float irx = invradius[0], iry = invradius[1], irz = invradius[2];

    float dn = sqrtf(dx*dx + dy*dy + dz*dz);
    float rdn = 1.0f / dn;
    dx *= rdn; dy *= rdn; dz *= rdn;

    const float C0 = 0.28209479177387814f;
    const float C1 = 0.4886025119029199f;
    float sh0 = C0;
    float sh1 = -C1 * vy;
    float sh2 =  C1 * vz;
    float sh3 = -C1 * vx;
    float sh4 =  1.0925484305920792f  * vx * vy;
    float sh5 = -1.0925484305920792f * vy * vz;
    float sh6 =  0.31539156525252005f * (2.0f*vz*vz - vx*vx - vy*vy);
    float sh7 = -1.0925484305920792f * vx * vz;
    float sh8 =  0.5462742152960396f  * (vx*vx - vy*vy);

    float idx = 1.0f / (dx + 1e-9f);
    float idy = 1.0f / (dy + 1e-9f);
    float idz = 1.0f / (dz + 1e-9f);

    float t1x = -ox*idx, t1y = -oy*idy, t1z = -oz*idz;
    float t2x = t1x+idx, t2y = t1y+idy, t2z = t1z+idz;
    float t0   = fmaxf(fmaxf(fmaxf(fminf(t1x,t2x), fminf(t1y,t2y)), fminf(t1z,t2z)), 0.0f);
    float tmax = fminf(fminf(fminf(fmaxf(t1x,t2x), fmaxf(t1y,t2y)), fmaxf(t1z,t2z)), 1e9f);

    float qx = dx / irx, qy = dy / iry, qz = dz / irz;
    float delta_scale = sqrtf(qx*qx + qy*qy + qz*qz);

    float t = t0;
    float light = 1.0f;
    float o0 = 0.0f, o1 = 0.0f, o2 = 0.0f;

    const float Rf = (float)GRID_R;
    const float cube_sz = 1.0f / (float)GRID_R;

    if (t0 < tmax) {
        // pipeline state: 4 slots, each 4 x uint4 (one 64 B record) + its dt
        uint4 b00, b01, b02, b03;
        uint4 b10, b11, b12, b13;
        uint4 b20, b21, b22, b23;
        uint4 b30, b31, b32, b33;
        float dt0, dt1, dt2, dt3;
        float tm = t0;   // geometry-march position (runs ahead of t)

#define ISSUE(K) do { \
        float pmx = (ox + tm*dx) * Rf; \
        float pmy = (oy + tm*dy) * Rf; \
        float pmz = (oz + tm*dz) * Rf; \
        float ffx = fminf(fmaxf(floorf(pmx), 0.0f), Rf - 1.0f); \
        float ffy = fminf(fmaxf(floorf(pmy), 0.0f), Rf - 1.0f); \
        float ffz = fminf(fmaxf(floorf(pmz), 0.0f), Rf - 1.0f); \
        int flat = (int)ffx * (GRID_R*GRID_R) + (int)ffy * GRID_R + (int)ffz; \
        const uint4* vp = (const uint4*)(vox_grid + (size_t)flat * PAD_DIM); \
        b##K##0 = vp[0]; b##K##1 = vp[1]; b##K##2 = vp[2]; b##K##3 = vp[3]; \
        float cx = pmx - ffx, cy = pmy - ffy, cz = pmz - ffz; \
        float a1x = -cx*idx, a1y = -cy*idy, a1z = -cz*idz; \
        float a2x = a1x+idx, a2y = a1y+idy, a2z = a1z+idz; \
        float e0 = fmaxf(fmaxf(fmaxf(fminf(a1x,a2x), fminf(a1y,a2y)), fminf(a1z,a2z)), 0.0f); \
        float e1 = fminf(fminf(fminf(fmaxf(a1x,a2x), fmaxf(a1y,a2y)), fmaxf(a1z,a2z)), 1e9f); \
        dt##K = (e1 - e0) * cube_sz + STEP_SIZE; \
        tm += dt##K; \
    } while (0)

#define CONSUME(K) do { \
        union { uint4 u[4]; __half2 h[16]; } rec; \
        rec.u[0] = b##K##0; rec.u[1] = b##K##1; \
        rec.u[2] = b##K##2; rec.u[3] = b##K##3; \
        float2 p0  = __half22float2(rec.h[0]); \
        float2 p1  = __half22float2(rec.h[1]); \
        float2 p2  = __half22float2(rec.h[2]); \
        float2 p3  = __half22float2(rec.h[3]); \
        float2 p4  = __half22float2(rec.h[4]); \
        float2 p5  = __half22float2(rec.h[5]); \
        float2 p6  = __half22float2(rec.h[6]); \
        float2 p7  = __half22float2(rec.h[7]); \
        float2 p8  = __half22float2(rec.h[8]); \
        float2 p9  = __half22float2(rec.h[9]); \
        float2 p10 = __half22float2(rec.h[10]); \
        float2 p11 = __half22float2(rec.h[11]); \
        float2 p12 = __half22float2(rec.h[12]); \
        float2 p13 = __half22float2(rec.h[13]); \
        float sigma = fmaxf(p13.y, 0.0f); \
        float att = __expf(-dt##K * sigma * delta_scale); \
        float weight = light * (1.0f - att); \
        float r0 = sh0*p0.x + sh1*p0.y + sh2*p1.x + sh3*p1.y \
                 + sh4*p2.x + sh5*p2.y + sh6*p3.x + sh7*p3.y + sh8*p4.x; \
        float r1 = sh0*p4.y + sh1*p5.x + sh2*p5.y + sh3*p6.x \
                 + sh4*p6.y + sh5*p7.x + sh6*p7.y + sh7*p8.x + sh8*p8.y; \
        float r2 = sh0*p9.x + sh1*p9.y + sh2*p10.x + sh3*p10.y \
                 + sh4*p11.x + sh5*p11.y + sh6*p12.x + sh7*p12.y + sh8*p13.x; \
        float g0 = 1.0f / (1.0f + __expf(-r0)); \
        float g1 = 1.0f / (1.0f + __expf(-r1)); \
        float g2 = 1.0f / (1.0f + __expf(-r2)); \
        o0 += weight * g0; \
        o1 += weight * g1; \
        o2 += weight * g2; \
        light *= att; \
        t += dt##K; \
    } while (0)

        // prologue: fill the 4-deep pipeline
        ISSUE(0); ISSUE(1); ISSUE(2); ISSUE(3);

        for (int s = 0; s < MAX_STEPS; s += 4) {
            CONSUME(0); if (t >= tmax || light < 1e-7f) break; ISSUE(0);
            CONSUME(1); if (t >= tmax || light < 1e-7f) break; ISSUE(1);
            CONSUME(2); if (t >= tmax || light < 1e-7f) break; ISSUE(2);
            CONSUME(3); if (t >= tmax || light < 1e-7f) break; ISSUE(3);
        }
#undef ISSUE
#undef CONSUME
    }

    out[3*i+0] = o0 + light * BG;
    out[3*i+1] = o1 + light * BG;
    out[3*i+2] = o2 + light * BG;
}

extern "C" void kernel_launch(void* const* d_in, const int* in_sizes, int n_in,
                              void* d_out, int out_size, void* d_ws, size_t ws_size,
                              hipStream_t stream) {
    const float* tree      = (const float*)d_in[0];
    const float* origins   = (const float*)d_in[1];
    const float* dirs      = (const float*)d_in[2];
    const float* viewdirs  = (const float*)d_in[3];
    const float* invradius = (const float*)d_in[4];
    float* out = (float*)d_out;

    int nB   = in_sizes[1] / 3;
    int nvox = in_sizes[0] / DATA_DIM;

    size_t need = (size_t)nvox * PAD_DIM * sizeof(__half);
    const int block = 256;

    __half* hgrid = (__half*)d_ws;
    int nconv = nvox * 8;  // one thread per 4 dst elements
    convert_kernel<<<(nconv + block - 1) / block, block, 0, stream>>>(
        tree, hgrid, nvox);
    VolumeRenderer_kernel_h<<<(nB + block - 1) / block, block, 0, stream>>>(
        hgrid, origins, dirs, viewdirs, invradius, out, nB);
    (void)need; (void)ws_size;
}

// Round 4
// 785.424 us; speedup vs baseline: 1.2085x; 1.0471x over previous
//
#include <hip/hip_runtime.h>
#include <hip/hip_fp16.h>
#include <math.h>

#define GRID_R 128
#define DATA_DIM 28
#define PAD_DIM 32
#define MAX_STEPS 256
#define STEP_SIZE 0.001f
#define BG 1.0f

// ---------------------------------------------------------------------------
// Pre-pass: fp32 grid (28 floats/voxel) -> fp16 grid (32 halfs/voxel, 64 B
// aligned records). 4 threads/voxel, 16 B stores.
// ---------------------------------------------------------------------------
__global__ __launch_bounds__(256) void convert_kernel(
    const float* __restrict__ tree, __half* __restrict__ dst, int nvox)
{
    int tid = blockIdx.x * blockDim.x + threadIdx.x;
    int v = tid >> 2;
    int q = tid & 3;
    if (v >= nvox) return;
    const float* src = tree + (size_t)v * DATA_DIM + q * 8;
    float4 s0 = *(const float4*)(src);              // q==3: elements 24..27
    float4 s1 = make_float4(0.f, 0.f, 0.f, 0.f);
    if (q < 3) s1 = *(const float4*)(src + 4);
    union { uint4 u; __half2 h[4]; } w;
    w.h[0] = __floats2half2_rn(s0.x, s0.y);
    w.h[1] = __floats2half2_rn(s0.z, s0.w);
    w.h[2] = __floats2half2_rn(s1.x, s1.y);
    w.h[3] = __floats2half2_rn(s1.z, s1.w);
    *(uint4*)(dst + (size_t)v * PAD_DIM + q * 8) = w.u;
}

// ---------------------------------------------------------------------------
// Main ray-march, fp16 grid, depth-4 software-pipelined gather.
// The trajectory (voxel index + dt) is data-independent, so geometry marches
// 4 steps ahead of consumption. Early exit is reference-style MASKING with a
// single break per 4-step chunk, so the whole chunk is one basic block and
// the compiler cannot sink the prefetch loads to their uses (round-3 failure:
// VGPR=44 proved the pipeline was collapsed). sched_barrier(0) pins slot
// boundaries. Grid supplies only 4 waves/SIMD -> VGPR<=128 keeps them all.
// ---------------------------------------------------------------------------
__global__ __launch_bounds__(256, 4) void VolumeRenderer_kernel_h(
    const __half* __restrict__ vox_grid,
    const float* __restrict__ origins,
    const float* __restrict__ dirs_in,
    const float* __restrict__ viewdirs,
    const float* __restrict__ invradius,
    float* __restrict__ out, int nB)
{
    int i = blockIdx.x * blockDim.x + threadIdx.x;
    if (i >= nB) return;

    float ox = origins[3*i+0], oy = origins[3*i+1], oz = origins[3*i+2];
    float dx = dirs_in[3*i+0], dy = dirs_in[3*i+1], dz = dirs_in[3*i+2];
    float vx = viewdirs[3*i+0], vy = viewdirs[3*i+1], vz = viewdirs[3*i+2];
    float irx = invradius[0], iry = invradius[1], irz = invradius[2];

    float dn = sqrtf(dx*dx + dy*dy + dz*dz);
    float rdn = 1.0f / dn;
    dx *= rdn; dy *= rdn; dz *= rdn;

    const float C0 = 0.28209479177387814f;
    const float C1 = 0.4886025119029199f;
    float sh0 = C0;
    float sh1 = -C1 * vy;
    float sh2 =  C1 * vz;
    float sh3 = -C1 * vx;
    float sh4 =  1.0925484305920792f  * vx * vy;
    float sh5 = -1.0925484305920792f * vy * vz;
    float sh6 =  0.31539156525252005f * (2.0f*vz*vz - vx*vx - vy*vy);
    float sh7 = -1.0925484305920792f * vx * vz;
    float sh8 =  0.5462742152960396f  * (vx*vx - vy*vy);

    float idx = 1.0f / (dx + 1e-9f);
    float idy = 1.0f / (dy + 1e-9f);
    float idz = 1.0f / (dz + 1e-9f);

    float t1x = -ox*idx, t1y = -oy*idy, t1z = -oz*idz;
    float t2x = t1x+idx, t2y = t1y+idy, t2z = t1z+idz;
    float t0   = fmaxf(fmaxf(fmaxf(fminf(t1x,t2x), fminf(t1y,t2y)), fminf(t1z,t2z)), 0.0f);
    float tmax = fminf(fminf(fminf(fmaxf(t1x,t2x), fmaxf(t1y,t2y)), fmaxf(t1z,t2z)), 1e9f);

    float qx = dx / irx, qy = dy / iry, qz = dz / irz;
    float delta_scale = sqrtf(qx*qx + qy*qy + qz*qz);

    float t = t0;
    float light = 1.0f;
    float o0 = 0.0f, o1 = 0.0f, o2 = 0.0f;

    const float Rf = (float)GRID_R;
    const float cube_sz = 1.0f / (float)GRID_R;

    if (t0 < tmax) {
        uint4 b00, b01, b02, b03;
        uint4 b10, b11, b12, b13;
        uint4 b20, b21, b22, b23;
        uint4 b30, b31, b32, b33;
        float dt0, dt1, dt2, dt3;
        float tm = t0;       // geometry-march position (runs 4 steps ahead)
        bool active = true;

// NOTE: s0 of the per-cell DDA is provably 0 for interior points
// (pos_t in [0,1)^3 => min(t1,t2) <= 0 on every axis), so only the exit
// distance e1 is computed. Clamps on floor() are load-safety for the
// overrun/masked phase where tm marches past the cube.
#define ISSUE(K) do { \
        float pmx = (ox + tm*dx) * Rf; \
        float pmy = (oy + tm*dy) * Rf; \
        float pmz = (oz + tm*dz) * Rf; \
        float ffx = fminf(fmaxf(floorf(pmx), 0.0f), 127.0f); \
        float ffy = fminf(fmaxf(floorf(pmy), 0.0f), 127.0f); \
        float ffz = fminf(fmaxf(floorf(pmz), 0.0f), 127.0f); \
        int flat = (int)ffx * (GRID_R*GRID_R) + (int)ffy * GRID_R + (int)ffz; \
        const uint4* vp = (const uint4*)(vox_grid + (size_t)flat * PAD_DIM); \
        b##K##0 = vp[0]; b##K##1 = vp[1]; b##K##2 = vp[2]; b##K##3 = vp[3]; \
        float cx = pmx - ffx, cy = pmy - ffy, cz = pmz - ffz; \
        float a1x = -cx*idx, a1y = -cy*idy, a1z = -cz*idz; \
        float a2x = a1x+idx, a2y = a1y+idy, a2z = a1z+idz; \
        float e1 = fminf(fminf(fminf(fmaxf(a1x,a2x), fmaxf(a1y,a2y)), fmaxf(a1z,a2z)), 1e9f); \
        dt##K = e1 * cube_sz + STEP_SIZE; \
        tm += dt##K; \
    } while (0)

// consume slot K (masked, reference semantics), then refill slot K for
// step s+4+K. One basic block; sched_barrier pins the slot boundary.
#define STEPM(K) do { \
        union { uint4 u[4]; __half2 h[16]; } rec; \
        rec.u[0] = b##K##0; rec.u[1] = b##K##1; \
        rec.u[2] = b##K##2; rec.u[3] = b##K##3; \
        float2 p0  = __half22float2(rec.h[0]); \
        float2 p1  = __half22float2(rec.h[1]); \
        float2 p2  = __half22float2(rec.h[2]); \
        float2 p3  = __half22float2(rec.h[3]); \
        float2 p4  = __half22float2(rec.h[4]); \
        float2 p5  = __half22float2(rec.h[5]); \
        float2 p6  = __half22float2(rec.h[6]); \
        float2 p7  = __half22float2(rec.h[7]); \
        float2 p8  = __half22float2(rec.h[8]); \
        float2 p9  = __half22float2(rec.h[9]); \
        float2 p10 = __half22float2(rec.h[10]); \
        float2 p11 = __half22float2(rec.h[11]); \
        float2 p12 = __half22float2(rec.h[12]); \
        float2 p13 = __half22float2(rec.h[13]); \
        float sigma = fmaxf(p13.y, 0.0f); \
        float att = __expf(-dt##K * sigma * delta_scale); \
        float attm = active ? att : 1.0f; \
        float weight = light * (1.0f - attm); \
        float r0 = sh0*p0.x + sh1*p0.y + sh2*p1.x + sh3*p1.y \
                 + sh4*p2.x + sh5*p2.y + sh6*p3.x + sh7*p3.y + sh8*p4.x; \
        float r1 = sh0*p4.y + sh1*p5.x + sh2*p5.y + sh3*p6.x \
                 + sh4*p6.y + sh5*p7.x + sh6*p7.y + sh7*p8.x + sh8*p8.y; \
        float r2 = sh0*p9.x + sh1*p9.y + sh2*p10.x + sh3*p10.y \
                 + sh4*p11.x + sh5*p11.y + sh6*p12.x + sh7*p12.y + sh8*p13.x; \
        float g0 = 1.0f / (1.0f + __expf(-r0)); \
        float g1 = 1.0f / (1.0f + __expf(-r1)); \
        float g2 = 1.0f / (1.0f + __expf(-r2)); \
        o0 += weight * g0; \
        o1 += weight * g1; \
        o2 += weight * g2; \
        light *= attm; \
        t += active ? dt##K : 0.0f; \
        active = active && (t < tmax) && (light >= 1e-7f); \
        ISSUE(K); \
        __builtin_amdgcn_sched_barrier(0); \
    } while (0)

        ISSUE(0); ISSUE(1); ISSUE(2); ISSUE(3);

        for (int s = 0; s < MAX_STEPS; s += 4) {
            STEPM(0);
            STEPM(1);
            STEPM(2);
            STEPM(3);
            if (!active) break;
        }
#undef ISSUE
#undef STEPM
    }

    out[3*i+0] = o0 + light * BG;
    out[3*i+1] = o1 + light * BG;
    out[3*i+2] = o2 + light * BG;
}

extern "C" void kernel_launch(void* const* d_in, const int* in_sizes, int n_in,
                              void* d_out, int out_size, void* d_ws, size_t ws_size,
                              hipStream_t stream) {
    const float* tree      = (const float*)d_in[0];
    const float* origins   = (const float*)d_in[1];
    const float* dirs      = (const float*)d_in[2];
    const float* viewdirs  = (const float*)d_in[3];
    const float* invradius = (const float*)d_in[4];
    float* out = (float*)d_out;

    int nB   = in_sizes[1] / 3;
    int nvox = in_sizes[0] / DATA_DIM;

    const int block = 256;
    __half* hgrid = (__half*)d_ws;
    int nconv = nvox * 4;   // 4 threads per voxel, 16 B stores
    convert_kernel<<<(nconv + block - 1) / block, block, 0, stream>>>(
        tree, hgrid, nvox);
    VolumeRenderer_kernel_h<<<(nB + block - 1) / block, block, 0, stream>>>(
        hgrid, origins, dirs, viewdirs, invradius, out, nB);
    (void)ws_size;
}

// Round 5
// 726.826 us; speedup vs baseline: 1.3060x; 1.0806x over previous
//
#include <hip/hip_runtime.h>
#include <hip/hip_fp16.h>
#include <math.h>

#define GRID_R 128
#define DATA_DIM 28
#define PAD_DIM 32
#define NSEG 8
#define SEG_STEPS 32
#define STEP_SIZE 0.001f
#define BG 1.0f

// ---------------------------------------------------------------------------
// Shared per-step geometry. Used by BOTH geom and march kernels so the
// t-sequence is bit-identical (same inlined IR -> same rounding/contraction).
// s0 of the cell DDA is provably exactly 0.0f for cx,cy,cz in [0,1]
// (min(a1,a2) <= 0 per axis, fmaxf(-0,0)=0), so only exit distance e1 is kept.
// ---------------------------------------------------------------------------
__device__ __forceinline__ float march_step(
    float t, float ox, float oy, float oz,
    float dx, float dy, float dz,
    float idx, float idy, float idz, int* flat)
{
    float px = (ox + t*dx) * 128.0f;
    float py = (oy + t*dy) * 128.0f;
    float pz = (oz + t*dz) * 128.0f;
    float fx = fminf(fmaxf(floorf(px), 0.0f), 127.0f);
    float fy = fminf(fmaxf(floorf(py), 0.0f), 127.0f);
    float fz = fminf(fmaxf(floorf(pz), 0.0f), 127.0f);
    *flat = (int)fx * (GRID_R*GRID_R) + (int)fy * GRID_R + (int)fz;
    float cx = px - fx, cy = py - fy, cz = pz - fz;
    float a1x = -cx*idx, a1y = -cy*idy, a1z = -cz*idz;
    float a2x = a1x+idx, a2y = a1y+idy, a2z = a1z+idz;
    float e1 = fminf(fminf(fmaxf(a1x,a2x), fmaxf(a1y,a2y)), fmaxf(a1z,a2z));
    e1 = fminf(e1, 1e9f);
    return e1 * (1.0f/128.0f) + STEP_SIZE;
}

// common ray setup
#define RAY_SETUP(i)                                                          \
    float ox = origins[3*(i)+0], oy = origins[3*(i)+1], oz = origins[3*(i)+2];\
    float dx = dirs_in[3*(i)+0], dy = dirs_in[3*(i)+1], dz = dirs_in[3*(i)+2];\
    float dn = sqrtf(dx*dx + dy*dy + dz*dz);                                  \
    float rdn = 1.0f / dn;                                                    \
    dx *= rdn; dy *= rdn; dz *= rdn;                                          \
    float idx = 1.0f / (dx + 1e-9f);                                          \
    float idy = 1.0f / (dy + 1e-9f);                                          \
    float idz = 1.0f / (dz + 1e-9f);                                          \
    float t1x = -ox*idx, t1y = -oy*idy, t1z = -oz*idz;                        \
    float t2x = t1x+idx, t2y = t1y+idy, t2z = t1z+idz;                        \
    float t0   = fmaxf(fmaxf(fmaxf(fminf(t1x,t2x), fminf(t1y,t2y)), fminf(t1z,t2z)), 0.0f); \
    float tmax = fminf(fminf(fminf(fmaxf(t1x,t2x), fmaxf(t1y,t2y)), fmaxf(t1z,t2z)), 1e9f);

// ---------------------------------------------------------------------------
// Pre-pass 1: fp32 grid -> fp16 grid, 32 halfs/voxel (64 B aligned records)
// ---------------------------------------------------------------------------
__global__ __launch_bounds__(256) void convert_kernel(
    const float* __restrict__ tree, __half* __restrict__ dst, int nvox)
{
    int tid = blockIdx.x * blockDim.x + threadIdx.x;
    int v = tid >> 2;
    int q = tid & 3;
    if (v >= nvox) return;
    const float* src = tree + (size_t)v * DATA_DIM + q * 8;
    float4 s0 = *(const float4*)(src);
    float4 s1 = make_float4(0.f, 0.f, 0.f, 0.f);
    if (q < 3) s1 = *(const float4*)(src + 4);
    union { uint4 u; __half2 h[4]; } w;
    w.h[0] = __floats2half2_rn(s0.x, s0.y);
    w.h[1] = __floats2half2_rn(s0.z, s0.w);
    w.h[2] = __floats2half2_rn(s1.x, s1.y);
    w.h[3] = __floats2half2_rn(s1.z, s1.w);
    *(uint4*)(dst + (size_t)v * PAD_DIM + q * 8) = w.u;
}

// ---------------------------------------------------------------------------
// Pre-pass 2: geometry checkpoints. One thread/ray; no memory gathers.
// ckpt[ray*8 + k] = exact t at step 32k (k=0 -> t0). Rays that exit early
// propagate t >= tmax into later checkpoints -> those segments are inactive.
// ---------------------------------------------------------------------------
__global__ __launch_bounds__(256) void geom_kernel(
    const float* __restrict__ origins,
    const float* __restrict__ dirs_in,
    float* __restrict__ ckpt, int nB)
{
    int i = blockIdx.x * blockDim.x + threadIdx.x;
    if (i >= nB) return;
    RAY_SETUP(i);

    float ck[NSEG];
    float t = t0;
    ck[0] = t0;
#pragma unroll
    for (int k = 1; k < NSEG; ++k) {
        if (t < tmax) {
            for (int j = 0; j < SEG_STEPS; ++j) {
                int fl;
                t += march_step(t, ox, oy, oz, dx, dy, dz, idx, idy, idz, &fl);
                if (t >= tmax) break;
            }
        }
        ck[k] = t;
    }
    float* cp = ckpt + (size_t)i * NSEG;
    *(float4*)(cp + 0) = make_float4(ck[0], ck[1], ck[2], ck[3]);
    *(float4*)(cp + 4) = make_float4(ck[4], ck[5], ck[6], ck[7]);
}

// ---------------------------------------------------------------------------
// Main march: 8 threads per ray (one per 32-step segment). 32768 waves
// (32/SIMD supply) so TLP hides the gather latency that ILP couldn't
// (rounds 3/4: compiler collapsed every software pipeline; VGPR 44/56).
// Segment results combine via 8-lane shuffle prefix products:
//   out = sum_j (prod_{k<j} L_k) * rgb_j ;  light = prod_j L_j
// Valid because termination is purely geometric: the reference light<1e-7
// cutoff is unreachable (max optical depth/step ~0.037 * 256 ~ 9.5).
// ---------------------------------------------------------------------------
__global__ __launch_bounds__(256, 8) void march_kernel(
    const __half* __restrict__ vox_grid,
    const float* __restrict__ origins,
    const float* __restrict__ dirs_in,
    const float* __restrict__ viewdirs,
    const float* __restrict__ invradius,
    const float* __restrict__ ckpt,
    float* __restrict__ out, int nB)
{
    int tid = blockIdx.x * blockDim.x + threadIdx.x;
    int ray = tid >> 3;
    int seg = tid & 7;
    if (ray >= nB) return;

    RAY_SETUP(ray);

    float vx = viewdirs[3*ray+0], vy = viewdirs[3*ray+1], vz = viewdirs[3*ray+2];
    float irx = invradius[0], iry = invradius[1], irz = invradius[2];
    float qx = dx / irx, qy = dy / iry, qz = dz / irz;
    float delta_scale = sqrtf(qx*qx + qy*qy + qz*qz);

    const float C0 = 0.28209479177387814f;
    const float C1 = 0.4886025119029199f;
    float sh0 = C0;
    float sh1 = -C1 * vy;
    float sh2 =  C1 * vz;
    float sh3 = -C1 * vx;
    float sh4 =  1.0925484305920792f  * vx * vy;
    float sh5 = -1.0925484305920792f * vy * vz;
    float sh6 =  0.31539156525252005f * (2.0f*vz*vz - vx*vx - vy*vy);
    float sh7 = -1.0925484305920792f * vx * vz;
    float sh8 =  0.5462742152960396f  * (vx*vx - vy*vy);

    float t = ckpt[(size_t)ray * NSEG + seg];
    float light = 1.0f;              // segment-local transmittance
    float o0 = 0.f, o1 = 0.f, o2 = 0.f;

    for (int j = 0; j < SEG_STEPS; ++j) {
        if (t >= tmax) break;
        int flat;
        float dt = march_step(t, ox, oy, oz, dx, dy, dz, idx, idy, idz, &flat);

        const uint4* vp = (const uint4*)(vox_grid + (size_t)flat * PAD_DIM);
        union { uint4 u[4]; __half2 h[16]; } rec;
        rec.u[0] = vp[0]; rec.u[1] = vp[1]; rec.u[2] = vp[2]; rec.u[3] = vp[3];

        float2 p0  = __half22float2(rec.h[0]);
        float2 p1  = __half22float2(rec.h[1]);
        float2 p2  = __half22float2(rec.h[2]);
        float2 p3  = __half22float2(rec.h[3]);
        float2 p4  = __half22float2(rec.h[4]);
        float2 p5  = __half22float2(rec.h[5]);
        float2 p6  = __half22float2(rec.h[6]);
        float2 p7  = __half22float2(rec.h[7]);
        float2 p8  = __half22float2(rec.h[8]);
        float2 p9  = __half22float2(rec.h[9]);
        float2 p10 = __half22float2(rec.h[10]);
        float2 p11 = __half22float2(rec.h[11]);
        float2 p12 = __half22float2(rec.h[12]);
        float2 p13 = __half22float2(rec.h[13]);

        float sigma = fmaxf(p13.y, 0.0f);
        float att = __expf(-dt * sigma * delta_scale);
        float weight = light * (1.0f - att);

        float r0 = sh0*p0.x + sh1*p0.y + sh2*p1.x + sh3*p1.y
                 + sh4*p2.x + sh5*p2.y + sh6*p3.x + sh7*p3.y + sh8*p4.x;
        float r1 = sh0*p4.y + sh1*p5.x + sh2*p5.y + sh3*p6.x
                 + sh4*p6.y + sh5*p7.x + sh6*p7.y + sh7*p8.x + sh8*p8.y;
        float r2 = sh0*p9.x + sh1*p9.y + sh2*p10.x + sh3*p10.y
                 + sh4*p11.x + sh5*p11.y + sh6*p12.x + sh7*p12.y + sh8*p13.x;

        float g0 = 1.0f / (1.0f + __expf(-r0));
        float g1 = 1.0f / (1.0f + __expf(-r1));
        float g2 = 1.0f / (1.0f + __expf(-r2));

        o0 += weight * g0;
        o1 += weight * g1;
        o2 += weight * g2;

        light *= att;
        t += dt;
    }

    // ---- 8-lane combine (lanes 8m..8m+7 hold segments 0..7 of one ray) ----
    float l0 = __shfl(light, 0, 8);
    float l1 = __shfl(light, 1, 8);
    float l2 = __shfl(light, 2, 8);
    float l3 = __shfl(light, 3, 8);
    float l4 = __shfl(light, 4, 8);
    float l5 = __shfl(light, 5, 8);
    float l6 = __shfl(light, 6, 8);
    float l7 = __shfl(light, 7, 8);

    float P = 1.0f;
    if (seg > 0) P *= l0;
    if (seg > 1) P *= l1;
    if (seg > 2) P *= l2;
    if (seg > 3) P *= l3;
    if (seg > 4) P *= l4;
    if (seg > 5) P *= l5;
    if (seg > 6) P *= l6;
    float total_light = l0*l1*l2*l3*l4*l5*l6*l7;

    o0 *= P; o1 *= P; o2 *= P;
    o0 += __shfl_xor(o0, 1, 8); o0 += __shfl_xor(o0, 2, 8); o0 += __shfl_xor(o0, 4, 8);
    o1 += __shfl_xor(o1, 1, 8); o1 += __shfl_xor(o1, 2, 8); o1 += __shfl_xor(o1, 4, 8);
    o2 += __shfl_xor(o2, 1, 8); o2 += __shfl_xor(o2, 2, 8); o2 += __shfl_xor(o2, 4, 8);

    if (seg == 0) {
        out[3*ray+0] = o0 + total_light * BG;
        out[3*ray+1] = o1 + total_light * BG;
        out[3*ray+2] = o2 + total_light * BG;
    }
}

extern "C" void kernel_launch(void* const* d_in, const int* in_sizes, int n_in,
                              void* d_out, int out_size, void* d_ws, size_t ws_size,
                              hipStream_t stream) {
    const float* tree      = (const float*)d_in[0];
    const float* origins   = (const float*)d_in[1];
    const float* dirs      = (const float*)d_in[2];
    const float* viewdirs  = (const float*)d_in[3];
    const float* invradius = (const float*)d_in[4];
    float* out = (float*)d_out;

    int nB   = in_sizes[1] / 3;
    int nvox = in_sizes[0] / DATA_DIM;

    const int block = 256;
    __half* hgrid = (__half*)d_ws;
    float* ckpt = (float*)((char*)d_ws + (size_t)nvox * PAD_DIM * sizeof(__half));

    int nconv = nvox * 4;
    convert_kernel<<<(nconv + block - 1) / block, block, 0, stream>>>(
        tree, hgrid, nvox);
    geom_kernel<<<(nB + block - 1) / block, block, 0, stream>>>(
        origins, dirs, ckpt, nB);
    int nmarch = nB * NSEG;
    march_kernel<<<(nmarch + block - 1) / block, block, 0, stream>>>(
        hgrid, origins, dirs, viewdirs, invradius, ckpt, out, nB);
    (void)ws_size;
}